// Round 11
// baseline (190.399 us; speedup 1.0000x reference)
//
#include <hip/hip_runtime.h>
#include <hip/hip_fp8.h>

#define N_NODES 50000
#define N_EDGES 800000
#define D_IN 128
#define HIDDEN 128
#define N_CLASSES 40

#define M_PAD 50048      // 782 * 64
#define CAP 64           // bucket capacity per node (deg ~ Binom(800k,1/50k))
#define EDGE_BATCH_BLOCKS 391  // 391*256*8 = 800768 >= 800000
#define GEMM1_BLOCKS (M_PAD / 64)               // 782
#define FUSE_BLOCKS (EDGE_BATCH_BLOCKS + GEMM1_BLOCKS)  // 1173

// r14 agg+gemm2 blocking (validated r3): 32-node tiles, 8 waves/block,
// 4 nodes/wave -> 12512 gather waves keep CUs saturated.
#define AGG_ROWS 32
#define AGG_NPW 4
#define AGG_GRID (M_PAD / AGG_ROWS)   // 1564

// r21 agg_out2 blocking: 1 node/wave, bucket row in registers, 24 edges
// in flight per tier (3 groups x 8-deep).
#define O2_GRID ((N_NODES + 3) / 4)   // 12500 blocks x 4 waves

typedef __attribute__((ext_vector_type(8))) short short8;
typedef __attribute__((ext_vector_type(4))) float floatx4;
typedef __attribute__((ext_vector_type(2))) float floatx2;

static __device__ __forceinline__ unsigned short f2bf(float f) {
    unsigned u = __float_as_uint(f);
    u = (u + 0x7fffu + ((u >> 16) & 1u)) >> 16;  // RNE
    return (unsigned short)u;
}
static __device__ __forceinline__ float bf2f(unsigned short b) {
    return __uint_as_float(((unsigned)b) << 16);
}
// fp8 e4m3 (OCP, gfx950) encode/decode via HIP type (HW cvt on gfx950)
static __device__ __forceinline__ unsigned char f2fp8(float v) {
    __hip_fp8_e4m3 t(v);
    return (unsigned char)t.__x;
}
static __device__ __forceinline__ float fp82f(unsigned char b) {
    __hip_fp8_e4m3 t;
    t.__x = (__hip_fp8_storage_t)b;
    return (float)t;
}

// ---------------------------------------------------------------------------
// prep: W1 -> transposed bf16, W2 -> transposed bf16, cnt -> 0.
// ---------------------------------------------------------------------------
#define KP_W1 128                      // 32768 elems / 256
#define KP_W2 40                       // 10240 elems / 256
#define KP_CNT 196                     // 50000 ints / 256
#define KP_GRID (KP_W1 + KP_W2 + KP_CNT)

__global__ __launch_bounds__(256) void prep_kernel(
    const float* __restrict__ W1l, const float* __restrict__ W1r,
    unsigned short* __restrict__ Wt1, const float* __restrict__ W2l,
    const float* __restrict__ W2r, unsigned short* __restrict__ Wt2,
    int* __restrict__ cnt) {
    int b = blockIdx.x;
    int t = threadIdx.x;
    if (b < KP_W1) {
        int i = b * 256 + t;  // < 256*128
        int n = i >> 7, k = i & 127;
        float v = (n < 128) ? W1l[k * 128 + n] : W1r[k * 128 + (n - 128)];
        Wt1[n * 128 + k] = f2bf(v);
    } else if (b < KP_W1 + KP_W2) {
        int i = (b - KP_W1) * 256 + t;  // < 80*128
        int n = i >> 7, k = i & 127;
        float v = (n < 40) ? W2l[k * 40 + n] : W2r[k * 40 + (n - 40)];
        Wt2[n * 128 + k] = f2bf(v);
    } else {
        int i = (b - KP_W1 - KP_W2) * 256 + t;
        if (i < N_NODES) cnt[i] = 0;
    }
}

// ---------------------------------------------------------------------------
// FUSED: bucket build + MFMA GEMM layer 1 in ONE dispatch (r12 win, r15
// config — measured best; r16 32-row variant neutral, r17/r18 mega-kernel
// variants failed: cooperative launch is not stream-capturable,
// persistent+launch_bounds(,8) spilled to scratch (VGPR 32, +170MB traffic,
// 6.7x slower). Do not revisit intra-launch sync.
//
// Bucket path: fixed-capacity USHORT buckets, ONE atomic per edge
// (r6/r8/r9/r10/r11 invariant — do not add passes). Overflow (p >= CAP) is
// statistically impossible (P(deg>64) ~ e-20), degrades to a dropped edge.
//
// GEMM path: block loads its 64x128 fp32 x-tile ONCE, converts to bf16 into
// LDS; 4 waves read frags from LDS. Outputs: cols 0..127 -> ylb fp8 e4m3
// (gathered 16x by agg), cols 128..255 -> yrb bf16 (read once).
// Row pad +8 -> 2-way LDS bank aliasing only (free, m136).
// Wave layout (m89/m120-verified): A[m=lane&15][k=quad*8+j],
// B[k=quad*8+j][n=lane&15], D col=lane&15, row=quad*4+reg.
// ---------------------------------------------------------------------------
#define A_LD 136  // 128 + 8 pad (ushort units); row stride 272 B

__global__ __launch_bounds__(256) void fused_build_gemm1_kernel(
    const int* __restrict__ src, const int* __restrict__ dst,
    int* __restrict__ cnt, unsigned short* __restrict__ bucket,
    const float* __restrict__ x, const unsigned short* __restrict__ Wt,
    unsigned char* __restrict__ ylb, unsigned short* __restrict__ yrb) {
    __shared__ unsigned short sA[64][A_LD];  // 17408 B (gemm path only)

    if (blockIdx.x < EDGE_BATCH_BLOCKS) {
        // ---------------- bucket path (no LDS, no sync) ----------------
        int i0 = (blockIdx.x * 256 + threadIdx.x) * 8;
        if (i0 >= N_EDGES) return;  // 800000 % 8 == 0 -> full groups only
        int4 d0 = *(const int4*)(dst + i0);
        int4 d1 = *(const int4*)(dst + i0 + 4);
        int4 s0 = *(const int4*)(src + i0);
        int4 s1 = *(const int4*)(src + i0 + 4);
        int p0 = atomicAdd(&cnt[d0.x], 1);
        int p1 = atomicAdd(&cnt[d0.y], 1);
        int p2 = atomicAdd(&cnt[d0.z], 1);
        int p3 = atomicAdd(&cnt[d0.w], 1);
        int p4 = atomicAdd(&cnt[d1.x], 1);
        int p5 = atomicAdd(&cnt[d1.y], 1);
        int p6 = atomicAdd(&cnt[d1.z], 1);
        int p7 = atomicAdd(&cnt[d1.w], 1);
        if (p0 < CAP) bucket[d0.x * CAP + p0] = (unsigned short)s0.x;
        if (p1 < CAP) bucket[d0.y * CAP + p1] = (unsigned short)s0.y;
        if (p2 < CAP) bucket[d0.z * CAP + p2] = (unsigned short)s0.z;
        if (p3 < CAP) bucket[d0.w * CAP + p3] = (unsigned short)s0.w;
        if (p4 < CAP) bucket[d1.x * CAP + p4] = (unsigned short)s1.x;
        if (p5 < CAP) bucket[d1.y * CAP + p5] = (unsigned short)s1.y;
        if (p6 < CAP) bucket[d1.z * CAP + p6] = (unsigned short)s1.z;
        if (p7 < CAP) bucket[d1.w * CAP + p7] = (unsigned short)s1.w;
        return;
    }

    // ------------------------- gemm1 path -------------------------
    const int wave = threadIdx.x >> 6;
    const int lane = threadIdx.x & 63;
    const int r = lane & 15, q = lane >> 4;
    const int m0 = (blockIdx.x - EDGE_BATCH_BLOCKS) * 64;
    const int n0 = wave * 64;
    const int t = threadIdx.x;

    // Stage + convert: 64 rows x 32 float4-groups = 2048 loads, 8/thread.
#pragma unroll
    for (int i = 0; i < 8; i++) {
        int g = t + i * 256;
        int row = g >> 5;             // 0..63
        int k4 = (g & 31) << 2;       // 0,4,...,124
        int gr = m0 + row;
        if (gr >= N_NODES) gr = N_NODES - 1;
        float4 v = *(const float4*)(x + (size_t)gr * 128 + k4);
        uint2 p;
        p.x = (unsigned)f2bf(v.x) | ((unsigned)f2bf(v.y) << 16);
        p.y = (unsigned)f2bf(v.z) | ((unsigned)f2bf(v.w) << 16);
        *(uint2*)&sA[row][k4] = p;
    }
    __syncthreads();

    floatx4 acc[4][4];
#pragma unroll
    for (int i = 0; i < 4; i++)
#pragma unroll
        for (int j = 0; j < 4; j++) acc[i][j] = (floatx4){0.f, 0.f, 0.f, 0.f};

#pragma unroll
    for (int kc = 0; kc < 128; kc += 32) {
        short8 a[4], bb[4];
#pragma unroll
        for (int mi = 0; mi < 4; mi++)
            a[mi] = *(const short8*)&sA[mi * 16 + r][kc + q * 8];
#pragma unroll
        for (int ni = 0; ni < 4; ni++)
            bb[ni] = *(const short8*)(Wt + (size_t)(n0 + ni * 16 + r) * 128 + kc + q * 8);
#pragma unroll
        for (int mi = 0; mi < 4; mi++)
#pragma unroll
            for (int ni = 0; ni < 4; ni++)
                acc[mi][ni] = __builtin_amdgcn_mfma_f32_16x16x32_bf16(
                    a[mi], bb[ni], acc[mi][ni], 0, 0, 0);
    }

#pragma unroll
    for (int mi = 0; mi < 4; mi++) {
        int rowb = m0 + mi * 16 + q * 4;
#pragma unroll
        for (int ni = 0; ni < 4; ni++) {
            int col = n0 + ni * 16 + r;
#pragma unroll
            for (int reg = 0; reg < 4; reg++) {
                int gr = rowb + reg;
                if (gr < N_NODES) {
                    float v = acc[mi][ni][reg];
                    if (col < 128)
                        ylb[(size_t)gr * 128 + col] = f2fp8(v);
                    else
                        yrb[(size_t)gr * 128 + (col - 128)] = f2bf(v);
                }
            }
        }
    }
}

// ---------------------------------------------------------------------------
// gemm2 sub-tile: one 16-row x (NN*16-col) MFMA tile, A from LDS.
// Col guard handles the 40-col split (zlb cols 0..39, zrb cols 40..79).
// ---------------------------------------------------------------------------
template <int NI0, int NN>
static __device__ __forceinline__ void gemm2_tile(
    const unsigned short (*sH)[A_LD], const unsigned short* __restrict__ Wt,
    unsigned short* __restrict__ zlb, unsigned short* __restrict__ zrb,
    int m0, int lrow0, int r, int q) {
    floatx4 acc[NN];
#pragma unroll
    for (int i = 0; i < NN; i++) acc[i] = (floatx4){0.f, 0.f, 0.f, 0.f};
#pragma unroll
    for (int kc = 0; kc < 128; kc += 32) {
        short8 a = *(const short8*)&sH[lrow0 + r][kc + q * 8];
        short8 b[NN];
#pragma unroll
        for (int ii = 0; ii < NN; ii++)
            b[ii] = *(const short8*)(Wt + (size_t)((NI0 + ii) * 16 + r) * 128 +
                                     kc + q * 8);
#pragma unroll
        for (int ii = 0; ii < NN; ii++)
            acc[ii] =
                __builtin_amdgcn_mfma_f32_16x16x32_bf16(a, b[ii], acc[ii], 0, 0, 0);
    }
    int rowb = m0 + q * 4;
#pragma unroll
    for (int ii = 0; ii < NN; ii++) {
        int col = (NI0 + ii) * 16 + r;
#pragma unroll
        for (int reg = 0; reg < 4; reg++) {
            int gr = rowb + reg;
            if (gr < N_NODES) {
                unsigned short v = f2bf(acc[ii][reg]);
                if (col < 40)
                    zlb[(size_t)gr * 40 + col] = v;
                else
                    zrb[(size_t)gr * 40 + (col - 40)] = v;
            }
        }
    }
}

// ---------------------------------------------------------------------------
// FUSED agg_relu1 + gemm2 (r14 blocking, r20 readlane gather).
// r22: launch bounds (512,8) -> (512,4). Profiling (r10) showed VGPR=32
// under (512,8): the allocator compressed below the ~50 live registers the
// 16-deep 2-node tier needs (16 load dests + accs + addrs), forcing
// dest-register reuse = serialized sub-batches — exactly the round-trips
// r20 was built to remove. (512,4) raises the budget to 128; the bound caps
// the ALLOCATOR, not achieved occupancy: if the kernel lands <= 64 VGPR we
// keep 4 blocks/CU AND full MLP.
// ---------------------------------------------------------------------------
__global__ __launch_bounds__(512, 4) void agg_gemm2_kernel(
    const unsigned short* __restrict__ yl8, const int* __restrict__ cnt,
    const unsigned short* __restrict__ bucket, const float2* __restrict__ b12,
    const unsigned int* __restrict__ yru, const unsigned short* __restrict__ Wt,
    unsigned short* __restrict__ zlb, unsigned short* __restrict__ zrb) {
    __shared__ unsigned short sH[AGG_ROWS][A_LD];  // 8704 B

    const int wave = threadIdx.x >> 6;  // 0..7
    const int l = threadIdx.x & 63;
    const int nodeBase = blockIdx.x * AGG_ROWS;

    // ---------------- phase 1: 2 node-pairs per wave ----------------------
#pragma unroll
    for (int pr = 0; pr < 2; pr++) {
        const int lrowA = wave * AGG_NPW + pr * 2;
        const int lrowB = lrowA + 1;
        int nA = min(nodeBase + lrowA, N_NODES - 1);
        int nB = min(nodeBase + lrowB, N_NODES - 1);
        int degA = cnt[nA], degB = cnt[nB];
        int reA = min(degA, CAP), reB = min(degB, CAP);
        // bucket rows -> registers (one coalesced 128B load each)
        int entA = (int)bucket[nA * CAP + l];
        int entB = (int)bucket[nB * CAP + l];
        floatx2 aA = {0.f, 0.f}, bA = {0.f, 0.f};
        floatx2 aB = {0.f, 0.f}, bB = {0.f, 0.f};
        int tiers = (max(reA, reB) + 7) >> 3;
        int e = 0;
        for (int tc = 0; tc < tiers; tc++, e += 8) {
            unsigned short uA[8], uB[8];
#pragma unroll
            for (int j = 0; j < 8; j++) {
                int sA_ = __builtin_amdgcn_readlane(entA, min(e + j, CAP - 1));
                uA[j] = yl8[(size_t)sA_ * 64 + l];
            }
#pragma unroll
            for (int j = 0; j < 8; j++) {
                int sB_ = __builtin_amdgcn_readlane(entB, min(e + j, CAP - 1));
                uB[j] = yl8[(size_t)sB_ * 64 + l];
            }
#pragma unroll
            for (int j = 0; j < 8; j++) {
                floatx2 fA = __builtin_amdgcn_cvt_pk_f32_fp8((int)uA[j], false);
                floatx2 fB = __builtin_amdgcn_cvt_pk_f32_fp8((int)uB[j], false);
                fA = (e + j < reA) ? fA : (floatx2){0.f, 0.f};
                fB = (e + j < reB) ? fB : (floatx2){0.f, 0.f};
                if (j & 1) { bA += fA; bB += fB; }
                else       { aA += fA; aB += fB; }
            }
        }
        // epilogue A
        {
            float invv = 1.0f / (float)max(degA, 1);
            unsigned ur = yru[(size_t)nA * 64 + l];
            float2 bv = b12[l];
            float ox = fmaxf((aA.x + bA.x) * invv + bf2f(ur & 0xffff) + bv.x, 0.0f);
            float oy = fmaxf((aA.y + bA.y) * invv + bf2f(ur >> 16) + bv.y, 0.0f);
            *(unsigned*)&sH[lrowA][2 * l] =
                (unsigned)f2bf(ox) | ((unsigned)f2bf(oy) << 16);
        }
        // epilogue B
        {
            float invv = 1.0f / (float)max(degB, 1);
            unsigned ur = yru[(size_t)nB * 64 + l];
            float2 bv = b12[l];
            float ox = fmaxf((aB.x + bB.x) * invv + bf2f(ur & 0xffff) + bv.x, 0.0f);
            float oy = fmaxf((aB.y + bB.y) * invv + bf2f(ur >> 16) + bv.y, 0.0f);
            *(unsigned*)&sH[lrowB][2 * l] =
                (unsigned)f2bf(ox) | ((unsigned)f2bf(oy) << 16);
        }
    }
    __syncthreads();

    // ---------------- phase 2: z = h @ Wt2, split across 8 waves ----------
    const int r = l & 15, q = l >> 4;
    const int rb = wave & 1;     // row block (16 rows each)
    const int part = wave >> 1;  // ni partition
    const int m0 = nodeBase + rb * 16;
    const int lrow0 = rb * 16;
    if (part == 0)
        gemm2_tile<0, 2>(sH, Wt, zlb, zrb, m0, lrow0, r, q);
    else if (part == 1)
        gemm2_tile<2, 1>(sH, Wt, zlb, zrb, m0, lrow0, r, q);
    else if (part == 2)
        gemm2_tile<3, 1>(sH, Wt, zlb, zrb, m0, lrow0, r, q);
    else
        gemm2_tile<4, 1>(sH, Wt, zlb, zrb, m0, lrow0, r, q);
}

// ---------------------------------------------------------------------------
// Fused agg + epilogue layer 2 (r21 rework — r20 mechanism ported):
// 1 node per wave (4/block, 12500 blocks -> 50000 waves, 3x r15's count).
// Bucket row -> registers ONCE; per-edge row index via __shfl(ent, e);
// 3 lane-groups x 8-deep = 24 edges in flight per tier. Unconditional
// clamped loads zeroed by select. Group partials combined with shfl;
// epilogue on lanes 0-19.
//   out[n][c] = (1/max(cnt,1)) * sum_j zl[bucket[n][j]][c] + zr[n][c] + b2[c]
// ---------------------------------------------------------------------------
__global__ __launch_bounds__(256) void agg_out2_kernel(
    const unsigned short* __restrict__ zlb, const unsigned short* __restrict__ zrb,
    const int* __restrict__ cnt, const unsigned short* __restrict__ bucket,
    const float* __restrict__ b2, float* __restrict__ out) {
    const int wave = threadIdx.x >> 6;
    const int l = threadIdx.x & 63;
    const int n = blockIdx.x * 4 + wave;
    if (n >= N_NODES) return;
    const int grp = l / 20;   // 0..2 gather groups; lanes 60-63 excluded
    const int cp = l % 20;    // column pair: cols 2cp, 2cp+1
    int deg = cnt[n];
    int re = min(deg, CAP);
    int ent = (int)bucket[n * CAP + l];  // full bucket row in registers
    float a0 = 0.f, a1 = 0.f;
    int tiers = (re + 23) / 24;
    for (int tc = 0; tc < tiers; tc++) {
        int e0 = tc * 24 + grp * 8;  // this group's 8 edges
        int s[8];
        unsigned u[8];
#pragma unroll
        for (int j = 0; j < 8; j++)
            s[j] = __shfl(ent, min(e0 + j, CAP - 1));
#pragma unroll
        for (int j = 0; j < 8; j++)
            u[j] = *(const unsigned*)(zlb + (size_t)s[j] * 40 + 2 * cp);
#pragma unroll
        for (int j = 0; j < 8; j++) {
            bool valid = (grp < 3) && (e0 + j < re);
            float v0 = valid ? bf2f(u[j] & 0xffff) : 0.0f;
            float v1 = valid ? bf2f(u[j] >> 16) : 0.0f;
            a0 += v0;
            a1 += v1;
        }
    }
    // combine the 3 group partials onto lanes 0-19
    float t0 = a0, t1 = a1;
    a0 = t0 + __shfl(t0, cp + 20) + __shfl(t0, cp + 40);
    a1 = t1 + __shfl(t1, cp + 20) + __shfl(t1, cp + 40);
    if (grp == 0) {
        float inv = 1.0f / (float)max(deg, 1);
        unsigned vr = *(const unsigned*)(zrb + (size_t)n * 40 + 2 * cp);
        float2 bb = *(const float2*)(b2 + 2 * cp);
        float2 o;
        o.x = a0 * inv + bf2f(vr & 0xffff) + bb.x;
        o.y = a1 * inv + bf2f(vr >> 16) + bb.y;
        *(float2*)(out + (size_t)n * 40 + 2 * cp) = o;
    }
}

// ---------------------------------------------------------------------------
extern "C" void kernel_launch(void* const* d_in, const int* in_sizes, int n_in,
                              void* d_out, int out_size, void* d_ws, size_t ws_size,
                              hipStream_t stream) {
    const float* x   = (const float*)d_in[0];
    const int*   ei  = (const int*)d_in[1];   // [2, E]: src row then dst row
    const float* W1l = (const float*)d_in[2];
    const float* b1  = (const float*)d_in[3];
    const float* W1r = (const float*)d_in[4];
    const float* W2l = (const float*)d_in[5];
    const float* b2  = (const float*)d_in[6];
    const float* W2r = (const float*)d_in[7];
    float* out = (float*)d_out;

    const int* src = ei;
    const int* dst = ei + N_EDGES;

    // Workspace layout (bytes), strictly non-overlapping, 16B-aligned:
    //  cnt    @ 0            200,000   (pad to 262,144)
    //  bucket @ 262,144    6,400,000   ends  6,662,144  (ushort)
    //  Wt1    @ 6,662,144     65,536   ends  6,727,680
    //  Wt2    @ 6,727,680     20,480   ends  6,748,160
    //  ylb    @ 19,560,448  6,400,000  ends 25,960,448  (fp8 e4m3)
    //  yrb    @ 25,960,448 12,800,000  ends 38,760,448  (bf16)
    //  zlb    @ 38,760,448  4,000,000  ends 42,760,448  (bf16)
    //  zrb    @ 42,760,448  4,000,000  ends 46,760,448  (< 256 MiB)
    char* ws = (char*)d_ws;
    int* cnt               = (int*)(ws);
    unsigned short* bucket = (unsigned short*)(ws + 262144);
    unsigned short* Wt1    = (unsigned short*)(ws + 6662144);
    unsigned short* Wt2    = (unsigned short*)(ws + 6727680);
    unsigned char*  ylb    = (unsigned char*)(ws + 19560448);
    unsigned short* yrb    = (unsigned short*)(ws + 25960448);
    unsigned short* zlb    = (unsigned short*)(ws + 38760448);
    unsigned short* zrb    = (unsigned short*)(ws + 42760448);

    // --- prep (weight transposes + cnt zero)
    prep_kernel<<<KP_GRID, 256, 0, stream>>>(W1l, W1r, Wt1, W2l, W2r, Wt2, cnt);

    // --- FUSED bucket build + layer-1 GEMM (r12 fusion, r15 config)
    fused_build_gemm1_kernel<<<FUSE_BLOCKS, 256, 0, stream>>>(
        src, dst, cnt, bucket, x, Wt1, ylb, yrb);

    // --- FUSED layer-1 aggregation + layer-2 GEMM (r20 gather, r22 bounds)
    agg_gemm2_kernel<<<AGG_GRID, 512, 0, stream>>>(
        (const unsigned short*)ylb, cnt, bucket, (const float2*)b1,
        (const unsigned int*)yrb, Wt2, zlb, zrb);

    // --- Layer 2 aggregation + output (r21: 1 node/wave, ent-register +
    //     shfl indices, 24-deep tiers)
    agg_out2_kernel<<<O2_GRID, 256, 0, stream>>>(
        zlb, zrb, cnt, bucket, b2, out);
}